// Round 1
// baseline (368.586 us; speedup 1.0000x reference)
//
#include <hip/hip_runtime.h>

// Problem: S=2048, B=32, H=1024, fp32.
// energies[b,s] = dec[b,:] . (enc[s,b,:] @ W^T + bias)  -> softmax over s.
// Algebraic reduction: energies[b,s] = enc[s,b,:] . v[b,:] + c[b],
//   v[b,h] = sum_k dec[b,k] * W[k,h],  c[b] = dec[b].bias (constant per row -> cancels in softmax).
// Floor: one 256 MB stream of enc @ ~6.3 TB/s ~= 41 us. proj/softmax are noise.
//
// R1 discriminating experiment:
//  - energy: PLAIN loads (nontemporal was never A/B'd; m13's 6.29 TB/s ceiling used plain float4)
//  - proj: 512 blocks (2/CU), float4 W loads, 16-way k-split -> 2 waves/SIMD, 16B/lane
//  - softmax: unchanged (provably tiny)

#define SS 2048
#define BB 32
#define HH 1024

typedef float vfloat4 __attribute__((ext_vector_type(4)));

// v[b,h] = sum_k dec[b,k] * W[k,h].
// grid = 512 blocks = (b, hc): hc selects a 64-wide h chunk (16 float4 columns).
// 256 threads = 16 k-groups x 16 h-threads; each thread: 64 k-iters of float4 W loads.
// dec row staged in LDS (broadcast reads); partials combined through LDS.
__global__ __launch_bounds__(256) void proj_kernel(const float* __restrict__ dec,
                                                   const float* __restrict__ W,
                                                   float* __restrict__ v) {
    __shared__ float ds[HH];
    __shared__ float part[16 * 64];
    const int b  = blockIdx.x >> 4;
    const int hc = blockIdx.x & 15;
    for (int i = threadIdx.x; i < HH; i += 256) ds[i] = dec[b * HH + i];
    __syncthreads();
    const int t   = threadIdx.x;
    const int ht  = t & 15;                 // float4 column within the 64-h chunk
    const int kg  = t >> 4;                 // 16 k-groups x 64 k each
    const int col = (hc << 4) + ht;         // float4 column in W (row stride HH/4)
    const int kbase = kg << 6;
    const vfloat4* __restrict__ Wp = (const vfloat4*)W;
    vfloat4 acc = {0.f, 0.f, 0.f, 0.f};
    #pragma unroll 8
    for (int k = 0; k < 64; ++k) {
        acc += ds[kbase + k] * Wp[(size_t)(kbase + k) * (HH / 4) + col];
    }
    ((vfloat4*)part)[(kg << 4) + ht] = acc;
    __syncthreads();
    if (t < 64) {
        float s = 0.f;
        #pragma unroll
        for (int g = 0; g < 16; ++g) s += part[(g << 6) + t];  // stride 64: 2 lanes/bank, free
        v[b * HH + (hc << 6) + t] = s;
    }
}

// e[b,s] = enc[s,b,:] . v[b,:].  One wave per (s,b); 16B plain loads over contiguous H row.
// enc streamed exactly once; v (128 KB) stays hot in L1/L2 by reuse, no nt hint needed.
__global__ __launch_bounds__(256) void energy_kernel(const float* __restrict__ enc,
                                                     const float* __restrict__ v,
                                                     float* __restrict__ e) {
    const int wid  = (blockIdx.x * 256 + threadIdx.x) >> 6;  // global wave id
    const int lane = threadIdx.x & 63;
    const int s = wid >> 5;        // wid / B
    const int b = wid & 31;        // wid % B
    const vfloat4* __restrict__ ep = (const vfloat4*)(enc + ((size_t)s * BB + b) * HH);
    const vfloat4* __restrict__ vp = (const vfloat4*)(v + (size_t)b * HH);
    float a0 = 0.f, a1 = 0.f;
    #pragma unroll
    for (int i = 0; i < 4; i += 2) {
        vfloat4 x0 = ep[(i    ) * 64 + lane];
        vfloat4 x1 = ep[(i + 1) * 64 + lane];
        vfloat4 w0 = vp[(i    ) * 64 + lane];
        vfloat4 w1 = vp[(i + 1) * 64 + lane];
        a0 += x0.x * w0.x + x0.y * w0.y + x0.z * w0.z + x0.w * w0.w;
        a1 += x1.x * w1.x + x1.y * w1.y + x1.z * w1.z + x1.w * w1.w;
    }
    float sum = a0 + a1;
    #pragma unroll
    for (int off = 32; off > 0; off >>= 1) sum += __shfl_down(sum, off, 64);
    if (lane == 0) e[b * SS + s] = sum;
}

// In-place softmax over each row of 2048. One block (256 thr) per b.
__global__ __launch_bounds__(256) void softmax_kernel(float* __restrict__ e) {
    const int b = blockIdx.x;
    vfloat4* p = (vfloat4*)(e + (size_t)b * SS);
    const int t    = threadIdx.x;
    const int wave = t >> 6;
    const int lane = t & 63;
    __shared__ float red[4];

    vfloat4 x0 = p[t];
    vfloat4 x1 = p[t + 256];

    float m = fmaxf(fmaxf(fmaxf(x0.x, x0.y), fmaxf(x0.z, x0.w)),
                    fmaxf(fmaxf(x1.x, x1.y), fmaxf(x1.z, x1.w)));
    #pragma unroll
    for (int off = 32; off > 0; off >>= 1) m = fmaxf(m, __shfl_down(m, off, 64));
    if (lane == 0) red[wave] = m;
    __syncthreads();
    m = fmaxf(fmaxf(red[0], red[1]), fmaxf(red[2], red[3]));
    __syncthreads();   // protect red[] before reuse for the sum

    x0.x = __expf(x0.x - m); x0.y = __expf(x0.y - m);
    x0.z = __expf(x0.z - m); x0.w = __expf(x0.w - m);
    x1.x = __expf(x1.x - m); x1.y = __expf(x1.y - m);
    x1.z = __expf(x1.z - m); x1.w = __expf(x1.w - m);

    float s = (x0.x + x0.y + x0.z + x0.w) + (x1.x + x1.y + x1.z + x1.w);
    #pragma unroll
    for (int off = 32; off > 0; off >>= 1) s += __shfl_down(s, off, 64);
    if (lane == 0) red[wave] = s;
    __syncthreads();
    const float inv = 1.0f / (red[0] + red[1] + red[2] + red[3]);

    x0 *= inv;
    x1 *= inv;
    p[t]       = x0;
    p[t + 256] = x1;
}

extern "C" void kernel_launch(void* const* d_in, const int* in_sizes, int n_in,
                              void* d_out, int out_size, void* d_ws, size_t ws_size,
                              hipStream_t stream) {
    const float* rnn = (const float*)d_in[0];   // [1,B,H]
    const float* enc = (const float*)d_in[1];   // [S,B,H]
    const float* W   = (const float*)d_in[2];   // [H,H]
    // d_in[3] = b_attn: adds a per-b constant to energies -> cancels in softmax.
    float* out = (float*)d_out;                 // [B,S]
    float* v   = (float*)d_ws;                  // [B,H] scratch (128 KB)

    proj_kernel<<<BB * 16, 256, 0, stream>>>(rnn, W, v);
    energy_kernel<<<(SS * BB) / 4, 256, 0, stream>>>(enc, v, out);
    softmax_kernel<<<BB, 256, 0, stream>>>(out);
}